// Round 3
// baseline (209.302 us; speedup 1.0000x reference)
//
#include <hip/hip_runtime.h>
#include <hip/hip_bf16.h>

#define LOG2E 1.4426950408889634f
// reference: mask(-1e9) BEFORE scale(/8); log2e folded into Q pre-scale
#define MASKVAL (-1.25e8f * LOG2E)

typedef __bf16 bf16x8 __attribute__((ext_vector_type(8)));
typedef __bf16 bf16x4 __attribute__((ext_vector_type(4)));
typedef short  shortx4 __attribute__((ext_vector_type(4)));
typedef float  floatx4 __attribute__((ext_vector_type(4)));

__device__ __forceinline__ floatx4 mfma16(bf16x8 a, bf16x8 b, floatx4 c) {
  return __builtin_amdgcn_mfma_f32_16x16x32_bf16(a, b, c, 0, 0, 0);
}

// 16x16x16 bf16 MFMA: B-operand layout (n=l15, k=quad*4+i) == S^T C-tile
// layout -> P feeds PV with zero cross-lane transforms.
__device__ __forceinline__ floatx4 mfma_pv(bf16x4 a, bf16x4 b, floatx4 c) {
#if __has_builtin(__builtin_amdgcn_mfma_f32_16x16x16_bf16)
  return __builtin_amdgcn_mfma_f32_16x16x16_bf16(a, b, c, 0, 0, 0);
#else
  shortx4 as, bs;
  __builtin_memcpy(&as, &a, 8);
  __builtin_memcpy(&bs, &b, 8);
  return __builtin_amdgcn_mfma_f32_16x16x16bf16_1k(as, bs, c, 0, 0, 0);
#endif
}

// async global->LDS, 16B per lane. Dest = wave-uniform base + lane*16.
__device__ __forceinline__ void load_lds16(const __bf16* g, __bf16* l) {
  __builtin_amdgcn_global_load_lds(
      (const __attribute__((address_space(1))) void*)g,
      (__attribute__((address_space(3))) void*)l, 16, 0, 0);
}

// ---------------------------------------------------------------------------
// Fold LoRA into weights, emit W_eff^T bf16 [ncols][1024].  Both weight sets
// in one launch: blockIdx.x < 48 -> qkv (ncols 3072), else proj (ncols 1024).
// ---------------------------------------------------------------------------
__global__ __launch_bounds__(256)
void fold_wt2(const float* __restrict__ Wq, const float* __restrict__ Aq,
              const float* __restrict__ Bq, __bf16* __restrict__ WTq,
              const float* __restrict__ Wp, const float* __restrict__ Ap,
              const float* __restrict__ Bp, __bf16* __restrict__ WTp) {
  __shared__ float tile[64][65];
  __shared__ float sLb[8][64];
  const int bx = blockIdx.x;
  const bool isQ = bx < 48;
  const float* W  = isQ ? Wq : Wp;
  const float* La = isQ ? Aq : Ap;
  const float* Lb = isQ ? Bq : Bp;
  __bf16* WT = isQ ? WTq : WTp;
  const int ncols = isQ ? 3072 : 1024;
  const int nt = (isQ ? bx : bx - 48) * 64;
  const int kt = blockIdx.y * 64;
  const int tid = threadIdx.x;
  const int tx = tid & 63, ty = tid >> 6;

  float rLa[8];
  *(float4*)&rLa[0] = *(const float4*)(La + (size_t)(kt + tx) * 8);
  *(float4*)&rLa[4] = *(const float4*)(La + (size_t)(kt + tx) * 8 + 4);

#pragma unroll
  for (int rep = 0; rep < 2; rep++) {
    int idx = tid + rep * 256;
    sLb[idx >> 6][idx & 63] = Lb[(size_t)(idx >> 6) * ncols + nt + (idx & 63)];
  }
#pragma unroll
  for (int rep = 0; rep < 16; rep++) {
    int i = rep * 4 + ty;
    tile[i][tx] = W[(size_t)(kt + i) * ncols + nt + tx];
  }
  __syncthreads();
#pragma unroll
  for (int rep = 0; rep < 16; rep++) {
    int i = rep * 4 + ty;
    int n = nt + i, k = kt + tx;
    float acc = tile[tx][i];
#pragma unroll
    for (int r = 0; r < 8; r++)
      acc += 2.0f * rLa[r] * sLb[r][i];  // LORA_SCALING = 2
    WT[(size_t)n * 1024 + k] = (__bf16)acc;
  }
}

__global__ __launch_bounds__(256)
void cast_x(const float* __restrict__ x, __bf16* __restrict__ o) {
  int i = blockIdx.x * 256 + threadIdx.x;
  float4 v = ((const float4*)x)[i];
  bf16x4 r = {(__bf16)v.x, (__bf16)v.y, (__bf16)v.z, (__bf16)v.w};
  ((bf16x4*)o)[i] = r;
}

// ---------------------------------------------------------------------------
// Fused QKV projection, swapped orientation: D[p][s] = sum_k WT[p][k] X[s][k].
// 128x128 tiles, BK=64, global_load_lds staging, XOR-swizzled LDS.
// Q channels (p<1024) pre-scaled by 0.125*LOG2E.
// V is written to vtb with keys PERMUTED within each 64-key chunk so the
// flash PV A-fragments are 16B-contiguous: key off (t=off>>4, qd=(off>>2)&3,
// r=off&3) stored at position (t>>1)*32 + qd*8 + (t&1)*4 + r.
// ---------------------------------------------------------------------------
__global__ __launch_bounds__(256)
void gemm_qkv(const __bf16* __restrict__ WT, const __bf16* __restrict__ X,
              const float* __restrict__ bias, __bf16* __restrict__ qk,
              __bf16* __restrict__ vtb) {
  const int K = 1024;
  __shared__ alignas(16) __bf16 As[128 * 64];
  __shared__ alignas(16) __bf16 Bs[128 * 64];
  const int tid = threadIdx.x;
  const int wave = tid >> 6, lane = tid & 63;
  const int wm = wave >> 1, wn = wave & 1;
  const int quad = lane >> 4, l15 = lane & 15;
  const int p0 = blockIdx.y * 128, s0 = blockIdx.x * 128;
  const int srow8 = lane >> 3, sc8 = lane & 7;
  const int sswz = sc8 ^ srow8;

  floatx4 acc[4][4] = {};

  for (int kb = 0; kb < K; kb += 64) {
    __syncthreads();
#pragma unroll
    for (int t = 0; t < 4; t++) {
      int rbase = (wave * 4 + t) * 8;
      int row = rbase + srow8;
      load_lds16(WT + (size_t)(p0 + row) * K + kb + sswz * 8, As + rbase * 64);
      load_lds16(X + (size_t)(s0 + row) * K + kb + sswz * 8, Bs + rbase * 64);
    }
    __syncthreads();
#pragma unroll
    for (int ks = 0; ks < 2; ks++) {
      bf16x8 af[4], bfv[4];
#pragma unroll
      for (int t = 0; t < 4; t++) {
        int ra = wm * 64 + t * 16 + l15;
        int rb = wn * 64 + t * 16 + l15;
        int ch = (ks * 4 + quad) ^ (l15 & 7);
        af[t]  = *(const bf16x8*)(As + ra * 64 + ch * 8);
        bfv[t] = *(const bf16x8*)(Bs + rb * 64 + ch * 8);
      }
#pragma unroll
      for (int mi = 0; mi < 4; mi++)
#pragma unroll
        for (int ni = 0; ni < 4; ni++)
          acc[mi][ni] = mfma16(af[mi], bfv[ni], acc[mi][ni]);
    }
  }

  const float qscale = (p0 < 1024) ? 0.125f * LOG2E : 1.0f;  // block-uniform
#pragma unroll
  for (int mi = 0; mi < 4; mi++) {
#pragma unroll
    for (int ni = 0; ni < 4; ni++) {
      int pb = p0 + wm * 64 + mi * 16 + quad * 4;  // channel base (mult of 4)
      int s  = s0 + wn * 64 + ni * 16 + l15;       // token
      int b = s >> 11, s2 = s & 2047;
      if (p0 < 2048) {  // q/k: uniform per block
        int part = pb >> 10, h = (pb & 1023) >> 6, dhb = pb & 63;
        bf16x4 o = {(__bf16)((acc[mi][ni][0] + bias[pb]) * qscale),
                    (__bf16)((acc[mi][ni][1] + bias[pb + 1]) * qscale),
                    (__bf16)((acc[mi][ni][2] + bias[pb + 2]) * qscale),
                    (__bf16)((acc[mi][ni][3] + bias[pb + 3]) * qscale)};
        *(bf16x4*)(qk + (size_t)part * 4194304 +
                   ((size_t)((b * 16 + h) * 2048 + s2)) * 64 + dhb) = o;
      } else {  // v -> v^T with per-chunk key permutation
        int h = (pb & 1023) >> 6, dhb = pb & 63;
        int off = s2 & 63, t = off >> 4, qd = (off >> 2) & 3, rr = off & 3;
        int ps2 = (s2 & ~63) | ((t >> 1) * 32 + qd * 8 + (t & 1) * 4 + rr);
#pragma unroll
        for (int r = 0; r < 4; r++)
          vtb[((size_t)((b * 16 + h) * 64 + dhb + r)) * 2048 + ps2] =
              (__bf16)(acc[mi][ni][r] + bias[pb + r]);
      }
    }
  }
}

// ---------------------------------------------------------------------------
// Output projection, 64x128 tile: grid (8, 64) = 512 blocks.  fp32 out + bias.
// ---------------------------------------------------------------------------
__global__ __launch_bounds__(256)
void gemm_proj(const __bf16* __restrict__ A, const __bf16* __restrict__ BT,
               const float* __restrict__ bias, float* __restrict__ Cout, int N) {
  const int K = 1024;
  __shared__ alignas(16) __bf16 As[64 * 64];
  __shared__ alignas(16) __bf16 Bs[128 * 64];
  const int tid = threadIdx.x;
  const int wave = tid >> 6, lane = tid & 63;
  const int wm = wave >> 1, wn = wave & 1;
  const int quad = lane >> 4, l15 = lane & 15;
  const int m0 = blockIdx.y * 64, n0 = blockIdx.x * 128;
  const int srow8 = lane >> 3, sc8 = lane & 7;
  const int sswz = sc8 ^ srow8;

  floatx4 acc[2][4] = {};

  for (int kb = 0; kb < K; kb += 64) {
    __syncthreads();
#pragma unroll
    for (int t = 0; t < 2; t++) {
      int rbase = (wave * 2 + t) * 8;
      load_lds16(A + (size_t)(m0 + rbase + srow8) * K + kb + sswz * 8,
                 As + rbase * 64);
    }
#pragma unroll
    for (int t = 0; t < 4; t++) {
      int rbase = (wave * 4 + t) * 8;
      load_lds16(BT + (size_t)(n0 + rbase + srow8) * K + kb + sswz * 8,
                 Bs + rbase * 64);
    }
    __syncthreads();
#pragma unroll
    for (int ks = 0; ks < 2; ks++) {
      bf16x8 af[2], bfv[4];
      int ch = (ks * 4 + quad) ^ (l15 & 7);
#pragma unroll
      for (int t = 0; t < 2; t++)
        af[t] = *(const bf16x8*)(As + (wm * 32 + t * 16 + l15) * 64 + ch * 8);
#pragma unroll
      for (int t = 0; t < 4; t++)
        bfv[t] = *(const bf16x8*)(Bs + (wn * 64 + t * 16 + l15) * 64 + ch * 8);
#pragma unroll
      for (int mi = 0; mi < 2; mi++)
#pragma unroll
        for (int ni = 0; ni < 4; ni++)
          acc[mi][ni] = mfma16(af[mi], bfv[ni], acc[mi][ni]);
    }
  }

#pragma unroll
  for (int mi = 0; mi < 2; mi++)
#pragma unroll
    for (int ni = 0; ni < 4; ni++) {
      int n = n0 + wn * 64 + ni * 16 + l15;
#pragma unroll
      for (int r = 0; r < 4; r++) {
        int m = m0 + wm * 32 + mi * 16 + quad * 4 + r;
        Cout[(size_t)m * N + n] = acc[mi][ni][r] + bias[n];
      }
    }
}

// ---------------------------------------------------------------------------
// Causal flash attention v14: paired uniform-cost strips.
// v13 post-mortem: quartile grouping balanced total work per CU but not
// concurrency -- short blocks retired early, leaving single latency-exposed
// blocks for the second half (occupancy decayed 16->4 waves/CU).  Also the
// in-loop vmcnt(4) force-drained the just-issued am_nxt load (L2 round trip
// per chunk on the critical path).
// v14: block = 4 waves, processes TWO 64-q strips sequentially: jb = 31-p
// then jb = p.  Cost = (32-p) + (p+1) = 33 chunks for EVERY block -> 512
// uniform blocks, 2/CU, 8 waves/CU constant for the whole kernel; stalls of
// one block fill under the co-resident one.  bh = bid&31 -> bh%8 = XCD, so
// each bh's K/V (512 KB) is L2-local to one XCD.
// Per strip: 4 waves lockstep over 64-key chunks, each wave owns one 16-q
// tile for the whole key range (no split-K, no merge).  K/V staged in LDS
// via global_load_lds (XOR swizzle), double-buffered, counted vmcnt(5)
// (= am_nxt + 4 stage DMAs in flight; v13's vmcnt(4) was an off-by-one that
// drained am_nxt).  amask word prefetched before the DMAs so it ages first.
// ---------------------------------------------------------------------------
__global__ __launch_bounds__(256)
void flash_attn(const __bf16* __restrict__ q, const __bf16* __restrict__ k,
                const __bf16* __restrict__ vt, const int* __restrict__ amask,
                __bf16* __restrict__ ctx) {
  const int S = 2048;
  __shared__ alignas(16) __bf16 Ks[2][64 * 64];
  __shared__ alignas(16) __bf16 Vs[2][64 * 64];
  const int bid = blockIdx.x;
  const int p = bid >> 5;            // pair index 0..15
  const int bh = bid & 31;           // bh%8 = XCD -> per-head K/V L2 locality
  const int b = bh >> 4, h = bh & 15;
  const int wave = threadIdx.x >> 6, lane = threadIdx.x & 63;
  const int quad = lane >> 4, l15 = lane & 15;
  const int srow8 = lane >> 3, sc8 = lane & 7;
  const int sswz = sc8 ^ srow8;

  const __bf16* qp  = q  + (size_t)bh * S * 64;
  const __bf16* kp0 = k  + (size_t)bh * S * 64;
  const __bf16* vp0 = vt + (size_t)bh * 64 * S;

  // stage chunk cc into buffer bb: each wave stages 16 rows of K and V.
  // K chunk rows = keys (contiguous 4096 elems); V chunk rows = dh
  // (row stride S).  XOR pre-swizzled global source, linear LDS dest.
  auto STAGE = [&](int bb, int cc) {
#pragma unroll
    for (int t = 0; t < 2; t++) {
      int rbase = (wave * 2 + t) * 8;
      load_lds16(kp0 + (size_t)cc * 4096 + (size_t)(rbase + srow8) * 64 +
                     sswz * 8,
                 &Ks[bb][rbase * 64]);
    }
#pragma unroll
    for (int t = 0; t < 2; t++) {
      int rbase = (wave * 2 + t) * 8;
      load_lds16(vp0 + (size_t)(rbase + srow8) * S + cc * 64 + sswz * 8,
                 &Vs[bb][rbase * 64]);
    }
  };

  auto run_strip = [&](int jb) {
    const int Q0 = jb * 64;
    const int qrow = Q0 + wave * 16 + l15;  // this wave's query rows

    // Q fragments (issued first -> oldest in vm queue, drained by 1st vmcnt)
    bf16x8 qf[2];
#pragma unroll
    for (int ks = 0; ks < 2; ks++)
      qf[ks] = *(const bf16x8*)(qp + (size_t)qrow * 64 + ks * 32 + quad * 8);

    // amask for chunk 0 BEFORE the DMA -> ages ahead of the stage ops
    int am_cur = amask[b * S + lane];
    int am_nxt = 0;

    STAGE(0, 0);

    float mrun = -1.0e30f, lrun = 0.0f;
    floatx4 oacc[4] = {};  // [dh-tile]; col(l15)=q, row(quad*4+r)=dh

    for (int c = 0; c <= jb; c++) {
      const int cur = c & 1;
      if (c < jb) {
        am_nxt = amask[b * S + (c + 1) * 64 + lane];  // before DMA: older
        STAGE(cur ^ 1, c + 1);
        // leave [am_nxt + stage(c+1) x4] = 5 in flight; drain stage(c)
        asm volatile("s_waitcnt vmcnt(5)" ::: "memory");
      } else {
        asm volatile("s_waitcnt vmcnt(0)" ::: "memory");
      }
      __builtin_amdgcn_s_barrier();          // chunk c data visible to all
      __builtin_amdgcn_sched_barrier(0);     // no ds_read hoist above barrier

      // S^T = K.Q^T: C col(l15)=q, row(quad*4+r)=key
      floatx4 st[4] = {};
      __builtin_amdgcn_s_setprio(1);
#pragma unroll
      for (int ks = 0; ks < 2; ks++) {
        const int ch = (ks * 4 + quad) ^ (l15 & 7);
        bf16x8 kf[4];
#pragma unroll
        for (int nt = 0; nt < 4; nt++)
          kf[nt] = *(const bf16x8*)(&Ks[cur][(nt * 16 + l15) * 64 + ch * 8]);
#pragma unroll
        for (int nt = 0; nt < 4; nt++)
          st[nt] = mfma16(kf[nt], qf[ks], st[nt]);
      }
      __builtin_amdgcn_s_setprio(0);

      unsigned long long pm = __ballot(am_cur == 0);
      if (pm == 0) {  // no padding (wave-uniform; true for all-ones mask)
        if (c == jb) {  // diagonal chunk: local causal mask
#pragma unroll
          for (int nt = 0; nt < 4; nt++) {
            int kl = nt * 16 + quad * 4;
#pragma unroll
            for (int r = 0; r < 4; r++) {
              bool masked = kl + r > wave * 16 + l15;
              st[nt][r] = masked ? MASKVAL : st[nt][r];
            }
          }
        }
      } else {
#pragma unroll
        for (int nt = 0; nt < 4; nt++) {
          int kl = nt * 16 + quad * 4;
#pragma unroll
          for (int r = 0; r < 4; r++) {
            bool pad = (pm >> (kl + r)) & 1ull;
            bool masked = pad || ((c == jb) && (kl + r > wave * 16 + l15));
            st[nt][r] = masked ? MASKVAL : st[nt][r];
          }
        }
      }

      // online softmax, log2 domain, per q = l15; defer-max (T13, THR=8)
      {
        float m4[4];
#pragma unroll
        for (int nt = 0; nt < 4; nt++)
          m4[nt] = fmaxf(fmaxf(st[nt][0], st[nt][1]),
                         fmaxf(st[nt][2], st[nt][3]));
        float rm = fmaxf(fmaxf(m4[0], m4[1]), fmaxf(m4[2], m4[3]));
        rm = fmaxf(rm, __shfl_xor(rm, 16, 64));
        rm = fmaxf(rm, __shfl_xor(rm, 32, 64));
        if (!__all(rm - mrun <= 8.0f)) {  // wave-uniform branch
          float mnew = fmaxf(mrun, rm);
          float al = exp2f(mrun - mnew);
          mrun = mnew;
          lrun *= al;
#pragma unroll
          for (int nd = 0; nd < 4; nd++)
#pragma unroll
            for (int r = 0; r < 4; r++) oacc[nd][r] *= al;
        }
        float s4[4];
#pragma unroll
        for (int nt = 0; nt < 4; nt++) {
          float p0v = exp2f(st[nt][0] - mrun);
          float p1v = exp2f(st[nt][1] - mrun);
          float p2v = exp2f(st[nt][2] - mrun);
          float p3v = exp2f(st[nt][3] - mrun);
          st[nt][0] = p0v; st[nt][1] = p1v;
          st[nt][2] = p2v; st[nt][3] = p3v;
          s4[nt] = (p0v + p1v) + (p2v + p3v);
        }
        float rs = (s4[0] + s4[1]) + (s4[2] + s4[3]);
        rs += __shfl_xor(rs, 16, 64);
        rs += __shfl_xor(rs, 32, 64);
        lrun += rs;
      }

      // pack P tiles (B-operand == C-layout)
      bf16x4 pB[4];
#pragma unroll
      for (int nt = 0; nt < 4; nt++) {
        bf16x4 pk = {(__bf16)st[nt][0], (__bf16)st[nt][1],
                     (__bf16)st[nt][2], (__bf16)st[nt][3]};
        pB[nt] = pk;
      }

      // O^T += V^T P^T ; one 16B V frag feeds key-subtiles 2tp and 2tp+1
      __builtin_amdgcn_s_setprio(1);
#pragma unroll
      for (int tp = 0; tp < 2; tp++) {
        const int chv = (tp * 4 + quad) ^ (l15 & 7);
#pragma unroll
        for (int nd = 0; nd < 4; nd++) {
          bf16x8 v8 =
              *(const bf16x8*)(&Vs[cur][(nd * 16 + l15) * 64 + chv * 8]);
          bf16x4 vA0 = {v8[0], v8[1], v8[2], v8[3]};
          bf16x4 vA1 = {v8[4], v8[5], v8[6], v8[7]};
          oacc[nd] = mfma_pv(vA0, pB[2 * tp], oacc[nd]);
          oacc[nd] = mfma_pv(vA1, pB[2 * tp + 1], oacc[nd]);
        }
      }
      __builtin_amdgcn_s_setprio(0);

      am_cur = am_nxt;
      __builtin_amdgcn_s_barrier();  // all waves done reading buf cur
    }

    // epilogue: direct normalize + store (no merge).  1/lrun exact under
    // defer-max (P and lrun share the same mrun reference).
    const float linv = 1.0f / lrun;
#pragma unroll
    for (int nd = 0; nd < 4; nd++) {
      bf16x4 o = {(__bf16)(oacc[nd][0] * linv), (__bf16)(oacc[nd][1] * linv),
                  (__bf16)(oacc[nd][2] * linv), (__bf16)(oacc[nd][3] * linv)};
      *(bf16x4*)(ctx + ((size_t)(b * 2048 + qrow)) * 1024 + h * 64 +
                 nd * 16 + quad * 4) = o;
    }
  };

  run_strip(31 - p);  // long strip of the pair
  run_strip(p);       // short strip: total 33 chunks for every block
}

// ---------------------------------------------------------------------------
extern "C" void kernel_launch(void* const* d_in, const int* in_sizes, int n_in,
                              void* d_out, int out_size, void* d_ws, size_t ws_size,
                              hipStream_t stream) {
  const float* x  = (const float*)d_in[0];
  const int*   am = (const int*)d_in[1];
  const float* Wq = (const float*)d_in[2];
  const float* bq = (const float*)d_in[3];
  const float* Aq = (const float*)d_in[4];
  const float* Bq = (const float*)d_in[5];
  const float* Wp = (const float*)d_in[6];
  const float* bp = (const float*)d_in[7];
  const float* Ap = (const float*)d_in[8];
  const float* Bp = (const float*)d_in[9];

  __bf16* wqkvT = (__bf16*)d_ws;                       // [3072][1024]
  __bf16* wpT   = wqkvT + (size_t)3072 * 1024;         // [1024][1024]
  __bf16* xbf   = wpT   + (size_t)1024 * 1024;         // [4096][1024]
  __bf16* qbuf  = xbf   + (size_t)4096 * 1024;         // [2][16][2048][64] (+kbuf)
  __bf16* vtbuf = qbuf  + (size_t)2 * 4194304;         // [2][16][64][2048] permuted
  __bf16* ctxb  = vtbuf + (size_t)4194304;             // [4096][1024]

  fold_wt2<<<dim3(64, 16), 256, 0, stream>>>(Wq, Aq, Bq, wqkvT,
                                             Wp, Ap, Bp, wpT);
  cast_x<<<4096, 256, 0, stream>>>(x, xbf);

  gemm_qkv<<<dim3(32, 24), 256, 0, stream>>>(wqkvT, xbf, bq, qbuf, vtbuf);
  flash_attn<<<512, 256, 0, stream>>>(qbuf, qbuf + 4194304, vtbuf, am, ctxb);
  gemm_proj<<<dim3(8, 64), 256, 0, stream>>>(ctxb, wpT, bp, (float*)d_out, 1024);
}